// Round 4
// baseline (392.878 us; speedup 1.0000x reference)
//
#include <hip/hip_runtime.h>
#include <cstdint>

#define BB 8
#define CC 128
#define HH 96
#define WW 160
#define HWsz (HH * WW)                 // 15360
#define TH 8
#define TW 32
#define CSTEP 8
#define HALO_H 16                      // TH + 8
#define SW 48                          // padded halo row stride (40 used + 8 pad), 12 blocks
#define CI_WORDS (HALO_H * SW)         // 768 words = 3 KB per channel
#define BUF_WORDS (CSTEP * CI_WORDS)   // 6144 words = 24 KB per buffer
#define NSLOTS (BUF_WORDS / 64)        // 96 wave-sized staging loads per chunk
#define NSTG 11                        // ceil(96/9) per wave (clamped dup benign)
#define NWAVES 9
#define NTHREADS (NWAVES * 64)         // 576
#define NCHUNKS (CC / CSTEP)           // 16
#define NBLOCKS (BB * (HH / TH) * (WW / TW))  // 480

__device__ __forceinline__ void g2l_dword(const float* g, float* l) {
  __builtin_amdgcn_global_load_lds((const __attribute__((address_space(1))) void*)g,
                                   (__attribute__((address_space(3))) void*)l,
                                   4, 0, 0);
}

// R4 structure: 8 px/lane half-channel compute (R1 shape, validated correct) on
// R3's counted-vmcnt pipeline. x1 lives in REGISTERS (prefetched 1 chunk ahead
// at the tail of compute), x2 in a 2-deep swizzled LDS ping-pong.
// FIFO per iter: [stage(k) 11][pf(k) 8][stage(k+1) 11]; manual vmcnt(19) drains
// stage(k) only; compiler's automatic wait for pf(k) use is vmcnt(11) -> keeps
// stage(k+1) in flight. No vmcnt(0) in the main loop.
// Barriers: two per chunk (R3 WAR/RAW proof carries over unchanged).
extern "C" __global__ void __launch_bounds__(NTHREADS, 2)
corr81_kernel(const float* __restrict__ x1, const float* __restrict__ x2,
              float* __restrict__ out)
{
  __shared__ __align__(16) float lds[2 * BUF_WORDS];   // 48 KB -> up to 3 blocks/CU

  const int tid  = threadIdx.x;
  const int wv   = tid >> 6;                            // dy 0..8 (wave-uniform)
  const int wvu  = __builtin_amdgcn_readfirstlane(wv);
  const int lane = tid & 63;
  const int h    = lane >> 5;        // channel-half: ci = 4h..4h+3 of the chunk
  const int r    = (lane >> 2) & 7;  // tile row 0..7
  const int s    = lane & 3;         // 8-px col slot (cols 8s..8s+7)

  // XCD-bijective swizzle (validated: FETCH 184->65 MB).
  const int bid0 = blockIdx.x;
  const int bid  = (bid0 & 7) * (NBLOCKS / 8) + (bid0 >> 3);

  const int wt = bid % (WW / TW);
  const int ht = (bid / (WW / TW)) % (HH / TH);
  const int b  = bid / ((WW / TW) * (HH / TH));
  const int h0 = ht * TH;
  const int w0 = wt * TW;

  // ---- chunk-invariant staging offsets, computed ONCE (R2 lesson: never
  // recompute per chunk). Dense linear LDS dest (slot = 64 words); the 4-word
  // block XOR swizzle (block ^ (row&3)) is applied on the GLOBAL source column
  // so source-permute and read-side swizzle are the same involution.
  uint32_t soff[NSTG]; uint32_t doff[NSTG];
#pragma unroll
  for (int i = 0; i < NSTG; ++i) {
    int idx = wvu + 9 * i; if (idx >= NSLOTS) idx = NSLOTS - 1;  // benign dup
    const int e    = idx * 64 + lane;
    const int ci   = e / CI_WORDS;
    const int rem  = e - ci * CI_WORDS;
    const int row  = rem / SW;
    const int colp = rem - row * SW;                 // physical col 0..47
    const int coll = colp ^ ((row & 3) << 2);        // logical col (involution)
    int gh = h0 + row  - 4; gh = gh < 0 ? 0 : (gh > HH - 1 ? HH - 1 : gh);
    int gw = w0 + coll - 4; gw = gw < 0 ? 0 : (gw > WW - 1 ? WW - 1 : gw);
    soff[i] = (uint32_t)((ci * HH + gh) * WW + gw);
    doff[i] = (uint32_t)(idx * 64);                  // wave-uniform -> SGPR
  }

  const float* x2b = x2 + (size_t)b * CC * HWsz;
  // per-lane x1 pointer: channels 4h..4h+3 (+q), row h0+r, cols w0+8s..
  const float* x1c = x1 + ((size_t)b * CC + 4 * h) * HWsz
                        + (size_t)(h0 + r) * WW + (w0 + 8 * s);

  // x2 LDS read bases. Bank algebra: group = (4(R&1) + (((2s+t) mod 8)^(R&3)))
  // mod 8 -> uniform 2 lanes/group per 16-lane phase, 4/group per 32 lanes =
  // the b128 floor (R1 measured 4 conflict-cyc/instr at this uniformity).
  const int R  = r + wv;             // halo row 0..15
  const int fx = (R & 3) << 2;
  int A[4];
#pragma unroll
  for (int t = 0; t < 4; ++t)
    A[t] = h * (4 * CI_WORDS) + R * SW + ((8 * s + 4 * t) ^ fx);

  float acc[9][8];
#pragma unroll
  for (int d = 0; d < 9; ++d)
#pragma unroll
    for (int p = 0; p < 8; ++p) acc[d][p] = 0.f;

  float4 pf[4][2];   // x1 prefetch regs, all accesses static-indexed (rule #20)

  // ---- prologue: stage(0), then pf(0)  (FIFO: [stage0 11][pf0 8])
#pragma unroll
  for (int i = 0; i < NSTG; ++i) g2l_dword(x2b + soff[i], &lds[doff[i]]);
#pragma unroll
  for (int q = 0; q < 4; ++q) {
    pf[q][0] = *(const float4*)(x1c + (size_t)q * HWsz);
    pf[q][1] = *(const float4*)(x1c + (size_t)q * HWsz + 4);
  }
  x1c += (size_t)CSTEP * HWsz;

#pragma unroll 1
  for (int k = 0; k < NCHUNKS - 1; ++k) {
    // [S] issue stage(k+1) into buf (k+1)&1 — 11 loads, precomputed offsets
    {
      const float* s2 = x2b + (size_t)(k + 1) * (CSTEP * HWsz);
      float* d2 = &lds[((k + 1) & 1) * BUF_WORDS];
#pragma unroll
      for (int i = 0; i < NSTG; ++i) g2l_dword(s2 + soff[i], d2 + doff[i]);
    }

    // [B] counted wait: drains stage(k); keeps pf(k)+stage(k+1) = 19 in flight
    __builtin_amdgcn_sched_barrier(0);
    asm volatile("s_waitcnt vmcnt(19)" ::: "memory");
    __builtin_amdgcn_sched_barrier(0);
    __builtin_amdgcn_s_barrier();
    __builtin_amdgcn_sched_barrier(0);

    // [D] compute chunk k: 16 ds_read_b128 + 576 FMA per lane; x1 from regs
    {
      const float* xb = &lds[(k & 1) * BUF_WORDS];
#pragma unroll
      for (int q = 0; q < 4; ++q) {
        const float4 a0 = pf[q][0];
        const float4 a1 = pf[q][1];
        const float av[8] = {a0.x, a0.y, a0.z, a0.w, a1.x, a1.y, a1.z, a1.w};
        float w16[16];
#pragma unroll
        for (int t = 0; t < 4; ++t) {
          const float4 f = *(const float4*)(xb + A[t] + q * CI_WORDS);
          w16[4*t+0] = f.x; w16[4*t+1] = f.y; w16[4*t+2] = f.z; w16[4*t+3] = f.w;
        }
#pragma unroll
        for (int d = 0; d < 9; ++d)
#pragma unroll
          for (int p = 0; p < 8; ++p)
            acc[d][p] = fmaf(av[p], w16[d + p], acc[d][p]);
      }
      // tail: issue pf(k+1) — lands after stage(k+1) in the vmcnt FIFO, so the
      // wait for pf(k+1) next iter is vmcnt(11): never drains the stage queue.
#pragma unroll
      for (int q = 0; q < 4; ++q) {
        pf[q][0] = *(const float4*)(x1c + (size_t)q * HWsz);
        pf[q][1] = *(const float4*)(x1c + (size_t)q * HWsz + 4);
      }
      x1c += (size_t)CSTEP * HWsz;
    }

    // [C2] WAR barrier
    __builtin_amdgcn_sched_barrier(0);
    __builtin_amdgcn_s_barrier();
    __builtin_amdgcn_sched_barrier(0);
  }

  // ---- peeled last chunk (k = 15, buf 1): nothing left to prefetch
  asm volatile("s_waitcnt vmcnt(0)" ::: "memory");
  __builtin_amdgcn_sched_barrier(0);
  __builtin_amdgcn_s_barrier();
  __builtin_amdgcn_sched_barrier(0);
  {
    const float* xb = &lds[((NCHUNKS - 1) & 1) * BUF_WORDS];
#pragma unroll
    for (int q = 0; q < 4; ++q) {
      const float4 a0 = pf[q][0];
      const float4 a1 = pf[q][1];
      const float av[8] = {a0.x, a0.y, a0.z, a0.w, a1.x, a1.y, a1.z, a1.w};
      float w16[16];
#pragma unroll
      for (int t = 0; t < 4; ++t) {
        const float4 f = *(const float4*)(xb + A[t] + q * CI_WORDS);
        w16[4*t+0] = f.x; w16[4*t+1] = f.y; w16[4*t+2] = f.z; w16[4*t+3] = f.w;
      }
#pragma unroll
      for (int d = 0; d < 9; ++d)
#pragma unroll
        for (int p = 0; p < 8; ++p)
          acc[d][p] = fmaf(av[p], w16[d + p], acc[d][p]);
    }
  }

  // ---- epilogue: combine channel-halves across lane^32 (R1-validated), /8.
  // h=0 lane writes cols 8s..8s+3, h=1 writes 8s+4..8s+7; partner sends the
  // half it does not own.
  float* op = out + (((size_t)b * 81 + (size_t)wv * 9) * HH + (h0 + r)) * WW
                  + (w0 + 8 * s + 4 * h);
#pragma unroll
  for (int d = 0; d < 9; ++d) {
    const float own0 = h ? acc[d][4] : acc[d][0];
    const float own1 = h ? acc[d][5] : acc[d][1];
    const float own2 = h ? acc[d][6] : acc[d][2];
    const float own3 = h ? acc[d][7] : acc[d][3];
    const float snd0 = h ? acc[d][0] : acc[d][4];
    const float snd1 = h ? acc[d][1] : acc[d][5];
    const float snd2 = h ? acc[d][2] : acc[d][6];
    const float snd3 = h ? acc[d][3] : acc[d][7];
    float4 v;
    v.x = (own0 + __shfl_xor(snd0, 32)) * 0.125f;
    v.y = (own1 + __shfl_xor(snd1, 32)) * 0.125f;
    v.z = (own2 + __shfl_xor(snd2, 32)) * 0.125f;
    v.w = (own3 + __shfl_xor(snd3, 32)) * 0.125f;
    *(float4*)(op + (size_t)d * HWsz) = v;
  }
}

extern "C" void kernel_launch(void* const* d_in, const int* in_sizes, int n_in,
                              void* d_out, int out_size, void* d_ws, size_t ws_size,
                              hipStream_t stream) {
  const float* x1 = (const float*)d_in[0];
  const float* x2 = (const float*)d_in[1];
  float* out = (float*)d_out;
  corr81_kernel<<<dim3(NBLOCKS), dim3(NTHREADS), 0, stream>>>(x1, x2, out);
}

// Round 5
// 391.695 us; speedup vs baseline: 1.0030x; 1.0030x over previous
//
#include <hip/hip_runtime.h>
#include <cstdint>

#define BB 8
#define CC 128
#define HH 96
#define WW 160
#define HWsz (HH * WW)                 // 15360
#define TH 8
#define TW 32
#define CSTEP 8
#define HALO_H 16                      // TH + 8
#define SW 48                          // padded halo row stride (40 used + 8 pad), 12 blocks
#define CI_WORDS (HALO_H * SW)         // 768 words = 3 KB per channel
#define BUF_WORDS (CSTEP * CI_WORDS)   // 6144 words = 24 KB per buffer
#define NSLOTS (BUF_WORDS / 64)        // 96 wave-sized staging loads per chunk
#define NSTG 11                        // ceil(96/9) per wave (clamped dup benign)
#define NWAVES 9
#define NTHREADS (NWAVES * 64)         // 576
#define NCHUNKS (CC / CSTEP)           // 16
#define NBLOCKS (BB * (HH / TH) * (WW / TW))  // 480

__device__ __forceinline__ void g2l_dword(const float* g, float* l) {
  __builtin_amdgcn_global_load_lds((const __attribute__((address_space(1))) void*)g,
                                   (__attribute__((address_space(3))) void*)l,
                                   4, 0, 0);
}

// R5 = R4 with ONE change: __launch_bounds__ 2nd arg 2 -> 1.
// Empirical semantics on this toolchain (R1: (576,5)->VGPR 48; R0/R3/R4:
// (576,2)->cap ~102): 2nd arg acts as min BLOCKS/CU. R4's live set
// (acc[9][8]=72 + pf regs 32 = 104) exceeded the 102 cap -> guaranteed spill
// (WRITE 198 MB). (576,1) caps at ~168-256; live ~150 fits. We trade down to
// 1 block/CU (9 waves): the counted-vmcnt pipeline + 4xb128->144cyc-FMA-chain
// ILP does the latency hiding that the second block was doing, and the LDS
// pipe (the measured R3 bottleneck: ~8.1k cyc/CU/chunk) now only serves
// 16 b128/chunk-wave at ~1/4 the conflicts (R4 validated: 2.2e6).
extern "C" __global__ void __launch_bounds__(NTHREADS, 1)
corr81_kernel(const float* __restrict__ x1, const float* __restrict__ x2,
              float* __restrict__ out)
{
  __shared__ __align__(16) float lds[2 * BUF_WORDS];   // 48 KB

  const int tid  = threadIdx.x;
  const int wv   = tid >> 6;                            // dy 0..8 (wave-uniform)
  const int wvu  = __builtin_amdgcn_readfirstlane(wv);
  const int lane = tid & 63;
  const int h    = lane >> 5;        // channel-half: ci = 4h..4h+3 of the chunk
  const int r    = (lane >> 2) & 7;  // tile row 0..7
  const int s    = lane & 3;         // 8-px col slot (cols 8s..8s+7)

  // XCD-bijective swizzle (validated: FETCH 184->65 MB).
  const int bid0 = blockIdx.x;
  const int bid  = (bid0 & 7) * (NBLOCKS / 8) + (bid0 >> 3);

  const int wt = bid % (WW / TW);
  const int ht = (bid / (WW / TW)) % (HH / TH);
  const int b  = bid / ((WW / TW) * (HH / TH));
  const int h0 = ht * TH;
  const int w0 = wt * TW;

  // ---- chunk-invariant staging offsets, computed ONCE (R2 lesson: never
  // recompute per chunk). Dense linear LDS dest (slot = 64 words); the 4-word
  // block XOR swizzle (block ^ (row&3)) is applied on the GLOBAL source column
  // so source-permute and read-side swizzle are the same involution.
  uint32_t soff[NSTG]; uint32_t doff[NSTG];
#pragma unroll
  for (int i = 0; i < NSTG; ++i) {
    int idx = wvu + 9 * i; if (idx >= NSLOTS) idx = NSLOTS - 1;  // benign dup
    const int e    = idx * 64 + lane;
    const int ci   = e / CI_WORDS;
    const int rem  = e - ci * CI_WORDS;
    const int row  = rem / SW;
    const int colp = rem - row * SW;                 // physical col 0..47
    const int coll = colp ^ ((row & 3) << 2);        // logical col (involution)
    int gh = h0 + row  - 4; gh = gh < 0 ? 0 : (gh > HH - 1 ? HH - 1 : gh);
    int gw = w0 + coll - 4; gw = gw < 0 ? 0 : (gw > WW - 1 ? WW - 1 : gw);
    soff[i] = (uint32_t)((ci * HH + gh) * WW + gw);
    doff[i] = (uint32_t)(idx * 64);                  // wave-uniform -> SGPR
  }

  const float* x2b = x2 + (size_t)b * CC * HWsz;
  // per-lane x1 pointer: channels 4h..4h+3 (+q), row h0+r, cols w0+8s..
  const float* x1c = x1 + ((size_t)b * CC + 4 * h) * HWsz
                        + (size_t)(h0 + r) * WW + (w0 + 8 * s);

  // x2 LDS read bases. Bank algebra: group = (4(R&1) + (((2s+t) mod 8)^(R&3)))
  // mod 8 -> uniform spread; R4 measured 2.2e6 total conflicts (6x down vs R3).
  const int R  = r + wv;             // halo row 0..15
  const int fx = (R & 3) << 2;
  int A[4];
#pragma unroll
  for (int t = 0; t < 4; ++t)
    A[t] = h * (4 * CI_WORDS) + R * SW + ((8 * s + 4 * t) ^ fx);

  float acc[9][8];
#pragma unroll
  for (int d = 0; d < 9; ++d)
#pragma unroll
    for (int p = 0; p < 8; ++p) acc[d][p] = 0.f;

  float4 pf[4][2];   // x1 prefetch regs, all accesses static-indexed (rule #20)

  // ---- prologue: stage(0), then pf(0)  (FIFO: [stage0 11][pf0 8])
#pragma unroll
  for (int i = 0; i < NSTG; ++i) g2l_dword(x2b + soff[i], &lds[doff[i]]);
#pragma unroll
  for (int q = 0; q < 4; ++q) {
    pf[q][0] = *(const float4*)(x1c + (size_t)q * HWsz);
    pf[q][1] = *(const float4*)(x1c + (size_t)q * HWsz + 4);
  }
  x1c += (size_t)CSTEP * HWsz;

#pragma unroll 1
  for (int k = 0; k < NCHUNKS - 1; ++k) {
    // [S] issue stage(k+1) into buf (k+1)&1 — 11 loads, precomputed offsets
    {
      const float* s2 = x2b + (size_t)(k + 1) * (CSTEP * HWsz);
      float* d2 = &lds[((k + 1) & 1) * BUF_WORDS];
#pragma unroll
      for (int i = 0; i < NSTG; ++i) g2l_dword(s2 + soff[i], d2 + doff[i]);
    }

    // [B] counted wait: drains stage(k); keeps pf(k)+stage(k+1) = 19 in flight
    __builtin_amdgcn_sched_barrier(0);
    asm volatile("s_waitcnt vmcnt(19)" ::: "memory");
    __builtin_amdgcn_sched_barrier(0);
    __builtin_amdgcn_s_barrier();
    __builtin_amdgcn_sched_barrier(0);

    // [D] compute chunk k: 16 ds_read_b128 + 288 FMA per lane; x1 from regs
    {
      const float* xb = &lds[(k & 1) * BUF_WORDS];
#pragma unroll
      for (int q = 0; q < 4; ++q) {
        const float4 a0 = pf[q][0];
        const float4 a1 = pf[q][1];
        const float av[8] = {a0.x, a0.y, a0.z, a0.w, a1.x, a1.y, a1.z, a1.w};
        float w16[16];
#pragma unroll
        for (int t = 0; t < 4; ++t) {
          const float4 f = *(const float4*)(xb + A[t] + q * CI_WORDS);
          w16[4*t+0] = f.x; w16[4*t+1] = f.y; w16[4*t+2] = f.z; w16[4*t+3] = f.w;
        }
#pragma unroll
        for (int d = 0; d < 9; ++d)
#pragma unroll
          for (int p = 0; p < 8; ++p)
            acc[d][p] = fmaf(av[p], w16[d + p], acc[d][p]);
      }
      // tail: issue pf(k+1) — lands after stage(k+1) in the vmcnt FIFO, so the
      // wait for pf(k+1) next iter is vmcnt(11): never drains the stage queue.
#pragma unroll
      for (int q = 0; q < 4; ++q) {
        pf[q][0] = *(const float4*)(x1c + (size_t)q * HWsz);
        pf[q][1] = *(const float4*)(x1c + (size_t)q * HWsz + 4);
      }
      x1c += (size_t)CSTEP * HWsz;
    }

    // [C2] WAR barrier
    __builtin_amdgcn_sched_barrier(0);
    __builtin_amdgcn_s_barrier();
    __builtin_amdgcn_sched_barrier(0);
  }

  // ---- peeled last chunk (k = 15, buf 1): nothing left to prefetch
  asm volatile("s_waitcnt vmcnt(0)" ::: "memory");
  __builtin_amdgcn_sched_barrier(0);
  __builtin_amdgcn_s_barrier();
  __builtin_amdgcn_sched_barrier(0);
  {
    const float* xb = &lds[((NCHUNKS - 1) & 1) * BUF_WORDS];
#pragma unroll
    for (int q = 0; q < 4; ++q) {
      const float4 a0 = pf[q][0];
      const float4 a1 = pf[q][1];
      const float av[8] = {a0.x, a0.y, a0.z, a0.w, a1.x, a1.y, a1.z, a1.w};
      float w16[16];
#pragma unroll
      for (int t = 0; t < 4; ++t) {
        const float4 f = *(const float4*)(xb + A[t] + q * CI_WORDS);
        w16[4*t+0] = f.x; w16[4*t+1] = f.y; w16[4*t+2] = f.z; w16[4*t+3] = f.w;
      }
#pragma unroll
      for (int d = 0; d < 9; ++d)
#pragma unroll
        for (int p = 0; p < 8; ++p)
          acc[d][p] = fmaf(av[p], w16[d + p], acc[d][p]);
    }
  }

  // ---- epilogue: combine channel-halves across lane^32 (R1/R4-validated), /8.
  float* op = out + (((size_t)b * 81 + (size_t)wv * 9) * HH + (h0 + r)) * WW
                  + (w0 + 8 * s + 4 * h);
#pragma unroll
  for (int d = 0; d < 9; ++d) {
    const float own0 = h ? acc[d][4] : acc[d][0];
    const float own1 = h ? acc[d][5] : acc[d][1];
    const float own2 = h ? acc[d][6] : acc[d][2];
    const float own3 = h ? acc[d][7] : acc[d][3];
    const float snd0 = h ? acc[d][0] : acc[d][4];
    const float snd1 = h ? acc[d][1] : acc[d][5];
    const float snd2 = h ? acc[d][2] : acc[d][6];
    const float snd3 = h ? acc[d][3] : acc[d][7];
    float4 v;
    v.x = (own0 + __shfl_xor(snd0, 32)) * 0.125f;
    v.y = (own1 + __shfl_xor(snd1, 32)) * 0.125f;
    v.z = (own2 + __shfl_xor(snd2, 32)) * 0.125f;
    v.w = (own3 + __shfl_xor(snd3, 32)) * 0.125f;
    *(float4*)(op + (size_t)d * HWsz) = v;
  }
}

extern "C" void kernel_launch(void* const* d_in, const int* in_sizes, int n_in,
                              void* d_out, int out_size, void* d_ws, size_t ws_size,
                              hipStream_t stream) {
  const float* x1 = (const float*)d_in[0];
  const float* x2 = (const float*)d_in[1];
  float* out = (float*)d_out;
  corr81_kernel<<<dim3(NBLOCKS), dim3(NTHREADS), 0, stream>>>(x1, x2, out);
}